// Round 10
// baseline (1005.004 us; speedup 1.0000x reference)
//
#include <hip/hip_runtime.h>
#include <math.h>

// Problem constants: T=4, B=4, C=2, H=W=128 (HW=16384), E=256, half=128.
#define HW 16384

typedef __attribute__((ext_vector_type(8))) _Float16 half8;
typedef __attribute__((ext_vector_type(4))) float f32x4;

// ---------------------------------------------------------------------------
// k_reorder2: BN-folded 2-plane fp16 split of (w*sc)*4096 into MFMA-A layout:
// plane[kb 4][tap 9][quad 4][oc 256][j 8], ic = kb*32+q*8+j.  (r7 proven)
// ---------------------------------------------------------------------------
__global__ __launch_bounds__(256)
void k_reorder2(const float* __restrict__ w1, const float* __restrict__ wres,
                const float* __restrict__ g1, const float* __restrict__ b1,
                const float* __restrict__ m1, const float* __restrict__ v1,
                const float* __restrict__ gr, const float* __restrict__ br,
                const float* __restrict__ mr, const float* __restrict__ vr,
                short* __restrict__ whi, short* __restrict__ wmid,
                short* __restrict__ rhi, short* __restrict__ rmid,
                float* __restrict__ bias1, float* __restrict__ biasr) {
    int i = blockIdx.x * 256 + threadIdx.x;
    if (i < 294912) {                 // 256 oc * 128 ic * 9 taps
        int n = i / 1152, rem = i % 1152;
        int ic = rem / 9, tap = rem % 9;
        float sc = g1[n] / sqrtf(v1[n] + 1e-5f);
        float wv = (w1[i] * sc) * 4096.0f;
        _Float16 h = (_Float16)wv;            // RNE
        float r1 = wv - (float)h;
        _Float16 m = (_Float16)r1;
        int kb = ic >> 5, q = (ic >> 3) & 3, j = ic & 7;
        size_t f = ((((size_t)(kb * 9 + tap)) * 4 + q) * 256 + n) * 8 + j;
        whi[f]  = __builtin_bit_cast(short, h);
        wmid[f] = __builtin_bit_cast(short, m);
    }
    if (i < 32768) {                  // 256 oc * 128 ic
        int n = i >> 7, ic = i & 127;
        float sc = gr[n] / sqrtf(vr[n] + 1e-5f);
        float wv = (wres[i] * sc) * 4096.0f;
        _Float16 h = (_Float16)wv;
        float r1 = wv - (float)h;
        _Float16 m = (_Float16)r1;
        int kb = ic >> 5, q = (ic >> 3) & 3, j = ic & 7;
        size_t f = (((size_t)kb * 4 + q) * 256 + n) * 8 + j;
        rhi[f]  = __builtin_bit_cast(short, h);
        rmid[f] = __builtin_bit_cast(short, m);
    }
    if (i < 256) {
        float sc1 = g1[i] / sqrtf(v1[i] + 1e-5f);
        bias1[i] = (b1[i] - m1[i] * sc1) * 4096.0f;
        float scr_ = gr[i] / sqrtf(vr[i] + 1e-5f);
        biasr[i] = (br[i] - mr[i] * scr_) * 4096.0f;
    }
}

// ---------------------------------------------------------------------------
// k_stA (ROUND 10): one launch per t = fused [proj conv+BN+LIF] + [temp
// conv+BN+LIF].  Block owns an 8x16 px tile; computes proj spikes on the
// 10x18 HALO tile into LDS (1.41x overcompute), temp conv reads LDS only.
// Cross-t races on vp/xout solved by PING-PONG (read prev buf, write next,
// owner-only writes) — no grid sync.  s1c written BIT-PACKED (16B per px).
// grid (8 cx, 16 ry, 4 b), block 256.  LDS ~45.4KB.
// ---------------------------------------------------------------------------
__global__ __launch_bounds__(256)
void k_stA(const float* __restrict__ xt, const float* __restrict__ xoutP,
           float* __restrict__ xoutN, const float* __restrict__ wp,
           const float* __restrict__ g0, const float* __restrict__ b0,
           const float* __restrict__ m0, const float* __restrict__ v0,
           const float* __restrict__ wt,
           const float* __restrict__ gt, const float* __restrict__ bt,
           const float* __restrict__ mt_, const float* __restrict__ vt,
           const float* __restrict__ vpP, float* __restrict__ vpN,
           float* __restrict__ vtm, unsigned char* __restrict__ s1t,
           int first, int last) {
    __shared__ float xin[480];            // [2 ch][12 r][20 c]
    __shared__ float wpls[2304];          // proj weights [oc][2][3][3]
    __shared__ float scls[128], ofls[128];
    __shared__ float wls[2304];           // temp weights
    __shared__ unsigned char sl[23040];   // s1 halo [p 180][ic 128], swizzled
    __shared__ float red[256];

    const int tid = threadIdx.x;
    const int gy0 = blockIdx.y * 8, gx0 = blockIdx.x * 16;
    const int b = blockIdx.z;

    for (int i = tid; i < 2304; i += 256) { wpls[i] = wp[i]; wls[i] = wt[i]; }
    if (tid < 128) {
        float sc = g0[tid] / sqrtf(v0[tid] + 1e-5f);
        scls[tid] = sc;
        ofls[tid] = b0[tid] - m0[tid] * sc;     // BN folded (r6-proven class)
    }
    for (int i = tid; i < 480; i += 256) {
        int ch = i / 240, rem = i % 240;
        int r = rem / 20, c = rem % 20;
        int gy = gy0 - 2 + r, gx = gx0 - 2 + c;
        float val = 0.f;
        if (gy >= 0 && gy < 128 && gx >= 0 && gx < 128) {
            int idx = ((b * 2 + ch) << 14) + (gy << 7) + gx;
            val = xt[idx];
            if (!first) val += xoutP[idx];
        }
        xin[(ch * 12 + r) * 20 + c] = val;
    }
    __syncthreads();

    // ---- proj phase: one thread per halo px (180 active) ----
    if (tid < 180) {
        const int p = tid;
        const int r = p / 18, c = p % 18;
        const int gy = gy0 - 1 + r, gx = gx0 - 1 + c;
        const bool inimg = (gy >= 0 && gy < 128 && gx >= 0 && gx < 128);
        const bool owned = (r >= 1 && r <= 8 && c >= 1 && c <= 16);
        unsigned int bits[4] = {0u, 0u, 0u, 0u};
        if (inimg) {
            float xw[2][3][3];
#pragma unroll
            for (int ch = 0; ch < 2; ++ch)
#pragma unroll
                for (int ky = 0; ky < 3; ++ky)
#pragma unroll
                    for (int kx = 0; kx < 3; ++kx)
                        xw[ch][ky][kx] = xin[(ch * 12 + r + ky) * 20 + c + kx];
            const int pix = (gy << 7) + gx;
#pragma unroll 4
            for (int oc = 0; oc < 128; ++oc) {
                float acc = 0.f;
#pragma unroll
                for (int ch = 0; ch < 2; ++ch)
#pragma unroll
                    for (int ky = 0; ky < 3; ++ky)
#pragma unroll
                        for (int kx = 0; kx < 3; ++kx)
                            acc = fmaf(wpls[((oc * 2 + ch) * 3 + ky) * 3 + kx],
                                       xw[ch][ky][kx], acc);
                float h = acc * scls[oc] + ofls[oc];
                int idx = ((b * 128 + oc) << 14) + pix;
                float v = first ? 0.f : vpP[idx];
                v = v + (h - v) * 0.5f;
                bool s = (v >= 1.0f);
                if (owned && !last) vpN[idx] = s ? 0.f : v;
                bits[oc >> 5] |= (s ? 1u : 0u) << (oc & 31);
            }
            if (owned)
                *(uint4*)(s1t + ((((size_t)b << 14) + pix) << 4)) =
                    make_uint4(bits[0], bits[1], bits[2], bits[3]);
        }
        // expand bits -> u8 into sl (zeros outside image = conv zero-pad)
#pragma unroll
        for (int icb = 0; icb < 16; ++icb) {
            unsigned int v8 = (bits[icb >> 2] >> ((icb & 3) * 8)) & 0xFFu;
            unsigned int lo = (v8 & 1u) | ((v8 & 2u) << 7) | ((v8 & 4u) << 14) | ((v8 & 8u) << 21);
            unsigned int hi = ((v8 >> 4) & 1u) | ((v8 & 32u) << 3) | ((v8 & 64u) << 10) | ((v8 & 128u) << 17);
            *(uint2*)&sl[p * 128 + ((icb ^ (p & 15)) * 8)] = make_uint2(lo, hi);
        }
    }
    __syncthreads();

    // ---- temp phase: 128 px x 2 ic-halves (split-K), LDS reduce ----
    {
        const int xq = tid & 127, hf = tid >> 7;
        const int ro = xq >> 4, co = xq & 15;
        float a0 = 0.f, a1 = 0.f;
#pragma unroll 1
        for (int ii = 0; ii < 8; ++ii) {
            const int icb = hf * 8 + ii;
            const float* w0 = &wls[icb * 72];
            const float* w1_ = &wls[1152 + icb * 72];
#pragma unroll
            for (int dy = 0; dy < 3; ++dy) {
#pragma unroll
                for (int dx = 0; dx < 3; ++dx) {
                    int pw = (ro + dy) * 18 + co + dx;
                    uint2 d = *(const uint2*)&sl[pw * 128 + ((icb ^ (pw & 15)) * 8)];
                    int tap = dy * 3 + dx;
#pragma unroll
                    for (int j = 0; j < 4; ++j) {
                        float f0 = (float)((d.x >> (8 * j)) & 0xFFu);
                        float f1 = (float)((d.y >> (8 * j)) & 0xFFu);
                        a0 = fmaf(w0[j * 9 + tap],       f0, a0);
                        a0 = fmaf(w0[(4 + j) * 9 + tap], f1, a0);
                        a1 = fmaf(w1_[j * 9 + tap],       f0, a1);
                        a1 = fmaf(w1_[(4 + j) * 9 + tap], f1, a1);
                    }
                }
            }
        }
        if (hf) { red[xq] = a0; red[128 + xq] = a1; }
        __syncthreads();
        if (!hf && !last) {
            a0 += red[xq]; a1 += red[128 + xq];
            const int gy = gy0 + ro, gx = gx0 + co;
#pragma unroll
            for (int oc = 0; oc < 2; ++oc) {
                float acc = oc ? a1 : a0;
                float sc = gt[oc] / sqrtf(vt[oc] + 1e-5f);
                float yv = (acc - mt_[oc]) * sc + bt[oc];
                int idx = ((b * 2 + oc) << 14) + (gy << 7) + gx;
                float v = first ? 0.f : vtm[idx];
                v = v + (yv - v) * 0.5f;
                bool s = (v >= 1.0f);
                vtm[idx]  = s ? 0.f : v;
                xoutN[idx] = s ? 1.0f : 0.f;
            }
        }
    }
}

// ---------------------------------------------------------------------------
// k_projF / k_tempF: FALLBACK (ws too small for ping-pong) — r7/r9 bodies
// with bit-packed s1c.
// ---------------------------------------------------------------------------
__global__ __launch_bounds__(256)
void k_projF(const float* __restrict__ xt, const float* __restrict__ xout,
             const float* __restrict__ wp,
             const float* __restrict__ g, const float* __restrict__ bb,
             const float* __restrict__ mm, const float* __restrict__ vv,
             float* __restrict__ vp, unsigned char* __restrict__ s1t, int first) {
    __shared__ float xin[2 * 10 * 36];
    const int tid = threadIdx.x;
    const int b   = blockIdx.z >> 2;
    const int ocq = blockIdx.z & 3;
    const int gy0 = blockIdx.y * 8, gx0 = blockIdx.x * 32;

    for (int i = tid; i < 680; i += 256) {
        int ch = i / 340, rem = i % 340;
        int r = rem / 34, c = rem % 34;
        int gy = gy0 - 1 + r, gx = gx0 - 1 + c;
        float val = 0.f;
        if (gy >= 0 && gy < 128 && gx >= 0 && gx < 128) {
            int idx = ((b * 2 + ch) << 14) + (gy << 7) + gx;
            val = xt[idx];
            if (!first) val += xout[idx];
        }
        xin[(ch * 10 + r) * 36 + c] = val;
    }
    __syncthreads();

    const int prow = tid >> 5, pcol = tid & 31;
    float xw[2][3][3];
#pragma unroll
    for (int ch = 0; ch < 2; ++ch)
#pragma unroll
        for (int ky = 0; ky < 3; ++ky)
#pragma unroll
            for (int kx = 0; kx < 3; ++kx)
                xw[ch][ky][kx] = xin[(ch * 10 + prow + ky) * 36 + pcol + kx];

    const int pix = ((gy0 + prow) << 7) + gx0 + pcol;
    const int oc_beg = ocq * 32;
    unsigned int pk = 0u;
#pragma unroll
    for (int oo = 0; oo < 32; ++oo) {
        const int oc = oc_beg + oo;
        float acc = 0.f;
#pragma unroll
        for (int ch = 0; ch < 2; ++ch)
#pragma unroll
            for (int ky = 0; ky < 3; ++ky)
#pragma unroll
                for (int kx = 0; kx < 3; ++kx)
                    acc = fmaf(wp[((oc * 2 + ch) * 3 + ky) * 3 + kx], xw[ch][ky][kx], acc);
        float sc = g[oc] / sqrtf(vv[oc] + 1e-5f);
        float h  = (acc - mm[oc]) * sc + bb[oc];
        int idx = ((b * 128 + oc) << 14) + pix;
        float v = first ? 0.f : vp[idx];
        v = v + (h - v) * 0.5f;
        bool s = (v >= 1.0f);
        vp[idx] = s ? 0.f : v;
        pk |= (s ? 1u : 0u) << oo;
    }
    *(unsigned int*)(s1t + ((((size_t)b << 14) + pix) << 4) + ocq * 4) = pk;
}

__global__ __launch_bounds__(256)
void k_tempF(const unsigned char* __restrict__ s1t, const float* __restrict__ wt,
             const float* __restrict__ g, const float* __restrict__ bb,
             const float* __restrict__ mm, const float* __restrict__ vv,
             float* __restrict__ vtm, float* __restrict__ xout, int first) {
    __shared__ unsigned char sl[49152];   // [icb 16][r 3][p 128] * 8B
    __shared__ float wls[2304];
    __shared__ float red[256];
    const int tid = threadIdx.x;
    const int b   = blockIdx.y;
    const int y0  = blockIdx.x;

    for (int i = tid; i < 2304; i += 256) wls[i] = wt[i];

    for (int i = tid; i < 384; i += 256) {     // 3 rows * 128 px, bit-packed
        int r = i >> 7, px = i & 127;
        int gy = y0 - 1 + r;
        uint4 d = make_uint4(0u, 0u, 0u, 0u);
        if (gy >= 0 && gy < 128)
            d = *(const uint4*)(s1t + ((((size_t)b << 14) + (gy << 7) + px) << 4));
        unsigned int bs[4] = {d.x, d.y, d.z, d.w};
#pragma unroll
        for (int icb = 0; icb < 16; ++icb) {
            unsigned int v8 = (bs[icb >> 2] >> ((icb & 3) * 8)) & 0xFFu;
            unsigned int lo = (v8 & 1u) | ((v8 & 2u) << 7) | ((v8 & 4u) << 14) | ((v8 & 8u) << 21);
            unsigned int hi = ((v8 >> 4) & 1u) | ((v8 & 32u) << 3) | ((v8 & 64u) << 10) | ((v8 & 128u) << 17);
            *(uint2*)&sl[(((icb * 3) + r) * 128 + (px ^ (icb & 7))) * 8] = make_uint2(lo, hi);
        }
    }
    __syncthreads();

    const int x = tid & 127, hf = tid >> 7;
    float a0 = 0.f, a1 = 0.f;
#pragma unroll 1
    for (int ii = 0; ii < 8; ++ii) {
        const int icb = hf * 8 + ii;
        int sw = icb & 7;
        const float* w0 = &wls[icb * 72];
        const float* w1_ = &wls[1152 + icb * 72];
#pragma unroll
        for (int dy = 0; dy < 3; ++dy) {
#pragma unroll
            for (int dx = 0; dx < 3; ++dx) {
                int xx = x - 1 + dx;
                if (xx < 0 || xx > 127) continue;
                uint2 d = *(const uint2*)&sl[((icb * 3 + dy) * 128 + (xx ^ sw)) * 8];
                int tap = dy * 3 + dx;
#pragma unroll
                for (int j = 0; j < 4; ++j) {
                    float f0 = (float)((d.x >> (8 * j)) & 0xFFu);
                    float f1 = (float)((d.y >> (8 * j)) & 0xFFu);
                    a0 = fmaf(w0[j * 9 + tap],        f0, a0);
                    a0 = fmaf(w0[(4 + j) * 9 + tap],  f1, a0);
                    a1 = fmaf(w1_[j * 9 + tap],       f0, a1);
                    a1 = fmaf(w1_[(4 + j) * 9 + tap], f1, a1);
                }
            }
        }
    }
    if (hf) { red[x] = a0; red[128 + x] = a1; }
    __syncthreads();
    if (!hf) {
        a0 += red[x]; a1 += red[128 + x];
#pragma unroll
        for (int oc = 0; oc < 2; ++oc) {
            float acc = (oc == 0) ? a0 : a1;
            float sc = g[oc] / sqrtf(vv[oc] + 1e-5f);
            float yv = (acc - mm[oc]) * sc + bb[oc];
            int idx = ((b * 2 + oc) << 14) + (y0 << 7) + x;
            float v = first ? 0.f : vtm[idx];
            v = v + (yv - v) * 0.5f;
            bool s = (v >= 1.0f);
            vtm[idx]  = s ? 0.f : v;
            xout[idx] = s ? 1.0f : 0.f;
        }
    }
}

// ---------------------------------------------------------------------------
// k_fused: r7 body exactly (prefetch of r9 removed — it cost 15 µs), with
// staging reading BIT-PACKED s1c (1 byte -> 8 fp16 spikes).
// grid (4 oc-tiles, 512 px-tiles), block 256 = 4 waves.
// ---------------------------------------------------------------------------
__global__ __launch_bounds__(256, 3)
void k_fused(const unsigned char* __restrict__ s1c,
             const short* __restrict__ whi, const short* __restrict__ wmid,
             const short* __restrict__ rhi, const short* __restrict__ rmid,
             const float* __restrict__ bias1, const float* __restrict__ biasr,
             float* __restrict__ out) {
    __shared__ __align__(16) char lds[52736];   // 16 icb * 206 entries * 16B

    const int tid = threadIdx.x;
    const int oc0 = blockIdx.x * 64;
    const int yb = blockIdx.y;
    const int b = yb >> 7, ry = (yb >> 2) & 31, cx = yb & 3;
    const int gy0 = ry * 4, gx0 = cx * 32;

    const int w   = tid >> 6, l = tid & 63;
    const int q   = l >> 4,  ln = l & 15;
    const int woc = w >> 1,  wpx = w & 1;

    f32x4 ba[2], brr[2];
#pragma unroll
    for (int mt = 0; mt < 2; ++mt)
#pragma unroll
        for (int rg = 0; rg < 4; ++rg) {
            int oc = oc0 + woc * 32 + mt * 16 + q * 4 + rg;
            ba[mt][rg]  = bias1[oc];
            brr[mt][rg] = biasr[oc];
        }

    const size_t wofs = ((size_t)q * 256 + oc0 + woc * 32 + ln) * 8;

    int pb[4], po[4];
#pragma unroll
    for (int nt = 0; nt < 4; ++nt) {
        int px = wpx * 64 + nt * 16 + ln;
        int prow = px >> 5, pcol = px & 31;
        pb[nt] = prow * 34 + pcol;
        po[nt] = ((gy0 + prow) << 7) + gx0 + pcol;
    }

    float va[4][2][4], vres[4][2][4];
#pragma unroll
    for (int nt = 0; nt < 4; ++nt)
#pragma unroll
        for (int mt = 0; mt < 2; ++mt)
#pragma unroll
            for (int rg = 0; rg < 4; ++rg) { va[nt][mt][rg] = 0.f; vres[nt][mt][rg] = 0.f; }

#pragma unroll 1
    for (int t = 0; t < 4; ++t) {
        const unsigned char* s1t = s1c + (size_t)t * 1048576;

        // ---- stage spike window from BITS: [icb 16][6x34] 8-ic fp16 ----
        for (int cc = tid; cc < 3264; cc += 256) {
            int p = cc >> 4, icb = cc & 15;
            int r = p / 34, c = p - r * 34;
            int gy = gy0 - 1 + r, gx = gx0 - 1 + c;
            unsigned int v8 = 0u;
            if (gy >= 0 && gy < 128 && gx >= 0 && gx < 128)
                v8 = s1t[((((size_t)b << 14) + (gy << 7) + gx) << 4) + icb];
            uint4 pk;                      // fp16 1.0 = 0x3C00
            pk.x = ((v8 & 1u)          | ((v8 & 2u)   << 15)) * 0x3C00u;
            pk.y = (((v8 >> 2) & 1u)   | ((v8 & 8u)   << 13)) * 0x3C00u;
            pk.z = (((v8 >> 4) & 1u)   | ((v8 & 32u)  << 11)) * 0x3C00u;
            pk.w = (((v8 >> 6) & 1u)   | ((v8 & 128u) << 9 )) * 0x3C00u;
            *(uint4*)(lds + (icb * 206 + p) * 16) = pk;
        }
        __syncthreads();

        f32x4 acc[4][2], accr[4][2];
#pragma unroll
        for (int nt = 0; nt < 4; ++nt)
#pragma unroll
            for (int mt = 0; mt < 2; ++mt) { acc[nt][mt] = ba[mt]; accr[nt][mt] = brr[mt]; }

        const short* bh = whi  + wofs;
        const short* bm = wmid + wofs;

#pragma unroll 1
        for (int kb = 0; kb < 4; ++kb) {
            const char* bkb = lds + (size_t)(kb * 4 + q) * 3296;   // 206*16
#pragma unroll
            for (int ky = 0; ky < 3; ++ky) {
#pragma unroll
                for (int kx = 0; kx < 3; ++kx) {
                    half8 B4[4];
#pragma unroll
                    for (int nt = 0; nt < 4; ++nt)
                        B4[nt] = *(const half8*)(bkb + (pb[nt] + ky * 34 + kx) * 16);
                    half8 AH[2], AM[2];
#pragma unroll
                    for (int mt = 0; mt < 2; ++mt) {
                        AH[mt] = *(const half8*)(bh + mt * 128);
                        AM[mt] = *(const half8*)(bm + mt * 128);
                    }
#pragma unroll
                    for (int nt = 0; nt < 4; ++nt)
#pragma unroll
                        for (int mt = 0; mt < 2; ++mt) {
                            acc[nt][mt] = __builtin_amdgcn_mfma_f32_16x16x32_f16(AH[mt], B4[nt], acc[nt][mt], 0, 0, 0);
                            acc[nt][mt] = __builtin_amdgcn_mfma_f32_16x16x32_f16(AM[mt], B4[nt], acc[nt][mt], 0, 0, 0);
                        }
                    if (ky == 1 && kx == 1) {
                        half8 RH[2], RM[2];
#pragma unroll
                        for (int mt = 0; mt < 2; ++mt) {
                            RH[mt] = *(const half8*)(rhi  + wofs + (size_t)kb * 8192 + mt * 128);
                            RM[mt] = *(const half8*)(rmid + wofs + (size_t)kb * 8192 + mt * 128);
                        }
#pragma unroll
                        for (int nt = 0; nt < 4; ++nt)
#pragma unroll
                            for (int mt = 0; mt < 2; ++mt) {
                                accr[nt][mt] = __builtin_amdgcn_mfma_f32_16x16x32_f16(RH[mt], B4[nt], accr[nt][mt], 0, 0, 0);
                                accr[nt][mt] = __builtin_amdgcn_mfma_f32_16x16x32_f16(RM[mt], B4[nt], accr[nt][mt], 0, 0, 0);
                            }
                    }
                    bh += 8192; bm += 8192;
                }
            }
        }
        __syncthreads();

        const float ds_ = 0.000244140625f;   // 2^-12, exact
        const size_t tb = ((size_t)((t * 4 + b) * 256 + oc0)) << 14;
#pragma unroll
        for (int mt = 0; mt < 2; ++mt)
#pragma unroll
            for (int rg = 0; rg < 4; ++rg) {
                const size_t ob = tb + ((size_t)(woc * 32 + mt * 16 + q * 4 + rg) << 14);
#pragma unroll
                for (int nt = 0; nt < 4; ++nt) {
                    float ha = acc[nt][mt][rg] * ds_;
                    float v = va[nt][mt][rg];
                    v = v + (ha - v) * 0.5f;
                    bool s = (v >= 1.0f);
                    va[nt][mt][rg] = s ? 0.f : v;
                    float sa = s ? 1.f : 0.f;

                    float hr = accr[nt][mt][rg] * ds_;
                    float u = vres[nt][mt][rg];
                    u = u + (hr - u) * 0.5f;
                    bool sr_ = (u >= 1.0f);
                    vres[nt][mt][rg] = sr_ ? 0.f : u;

                    out[ob + po[nt]] = sa + (sr_ ? 1.f : 0.f);
                }
            }
    }
}

// ---------------------------------------------------------------------------
// Workspace (primary, ping-pong path), bytes:
//   s1c(bits) @ 0           4,194,304   [T][B][pix][16B]
//   vpP0      @ 4,194,304  33,554,432
//   vpP1      @ 37,748,736 33,554,432
//   vtm       @ 71,303,168    524,288
//   xoutP0    @ 71,827,456    524,288
//   xoutP1    @ 72,351,744    524,288
//   whi       @ 72,876,032    589,824
//   wmid      @ 73,465,856    589,824
//   rhi       @ 74,055,680     65,536
//   rmid      @ 74,121,216     65,536
//   bias1     @ 74,186,752      1,024
//   biasr     @ 74,187,776      1,024   total 74,188,800
// Fallback (ws < 74.2MB): single vp/xout, same offsets minus vpP1/xoutP1 use.
// ---------------------------------------------------------------------------
extern "C" void kernel_launch(void* const* d_in, const int* in_sizes, int n_in,
                              void* d_out, int out_size, void* d_ws, size_t ws_size,
                              hipStream_t stream) {
    const float* x      = (const float*)d_in[0];
    const float* w_proj = (const float*)d_in[1];
    const float* g0 = (const float*)d_in[2];
    const float* b0 = (const float*)d_in[3];
    const float* m0 = (const float*)d_in[4];
    const float* v0 = (const float*)d_in[5];
    const float* w_temp = (const float*)d_in[6];
    const float* gt = (const float*)d_in[7];
    const float* bt = (const float*)d_in[8];
    const float* mt = (const float*)d_in[9];
    const float* vt = (const float*)d_in[10];
    const float* w1 = (const float*)d_in[11];
    const float* g1 = (const float*)d_in[12];
    const float* b1 = (const float*)d_in[13];
    const float* m1 = (const float*)d_in[14];
    const float* v1 = (const float*)d_in[15];
    const float* w_res = (const float*)d_in[16];
    const float* gr = (const float*)d_in[17];
    const float* br = (const float*)d_in[18];
    const float* mr = (const float*)d_in[19];
    const float* vr = (const float*)d_in[20];

    char* ws = (char*)d_ws;
    unsigned char* s1c = (unsigned char*)ws;
    float* vpP0  = (float*)(ws + 4194304);
    float* vpP1  = (float*)(ws + 37748736);
    float* vtm   = (float*)(ws + 71303168);
    float* xoutP0= (float*)(ws + 71827456);
    float* xoutP1= (float*)(ws + 72351744);
    short* whi   = (short*)(ws + 72876032);
    short* wmid  = (short*)(ws + 73465856);
    short* rhi   = (short*)(ws + 74055680);
    short* rmid  = (short*)(ws + 74121216);
    float* bias1 = (float*)(ws + 74186752);
    float* biasr = (float*)(ws + 74187776);
    const bool pingpong = (ws_size >= (size_t)74188800);

    k_reorder2<<<dim3(1152), dim3(256), 0, stream>>>(
        w1, w_res, g1, b1, m1, v1, gr, br, mr, vr,
        whi, wmid, rhi, rmid, bias1, biasr);

    if (pingpong) {
        for (int t = 0; t < 4; ++t) {
            const float* xt = x + (size_t)t * 131072;
            unsigned char* s1t = s1c + (size_t)t * 1048576;
            float* vpR = (t & 1) ? vpP1 : vpP0;
            float* vpW = (t & 1) ? vpP0 : vpP1;
            float* xoR = (t & 1) ? xoutP1 : xoutP0;
            float* xoW = (t & 1) ? xoutP0 : xoutP1;
            k_stA<<<dim3(8, 16, 4), dim3(256), 0, stream>>>(
                xt, xoR, xoW, w_proj, g0, b0, m0, v0,
                w_temp, gt, bt, mt, vt, vpR, vpW, vtm, s1t,
                t == 0, t == 3);
        }
    } else {
        for (int t = 0; t < 4; ++t) {
            const float* xt = x + (size_t)t * 131072;
            unsigned char* s1t = s1c + (size_t)t * 1048576;
            k_projF<<<dim3(4, 16, 16), dim3(256), 0, stream>>>(
                xt, xoutP0, w_proj, g0, b0, m0, v0, vpP0, s1t, t == 0);
            k_tempF<<<dim3(128, 4), dim3(256), 0, stream>>>(
                s1t, w_temp, gt, bt, mt, vt, vtm, xoutP0, t == 0);
        }
    }

    k_fused<<<dim3(4, 512), dim3(256), 0, stream>>>(
        s1c, whi, wmid, rhi, rmid, bias1, biasr, (float*)d_out);
}

// Round 11
// 806.523 us; speedup vs baseline: 1.2461x; 1.2461x over previous
//
#include <hip/hip_runtime.h>
#include <math.h>

// Problem constants: T=4, B=4, C=2, H=W=128 (HW=16384), E=256, half=128.
#define HW 16384

typedef __attribute__((ext_vector_type(8))) _Float16 half8;
typedef __attribute__((ext_vector_type(4))) float f32x4;

// ---------------------------------------------------------------------------
// k_reorder2: BN-folded 2-plane fp16 split of (w*sc)*4096 into MFMA-A layout:
// plane[kb 4][tap 9][quad 4][oc 256][j 8], ic = kb*32+q*8+j.  (r7 proven)
// ---------------------------------------------------------------------------
__global__ __launch_bounds__(256)
void k_reorder2(const float* __restrict__ w1, const float* __restrict__ wres,
                const float* __restrict__ g1, const float* __restrict__ b1,
                const float* __restrict__ m1, const float* __restrict__ v1,
                const float* __restrict__ gr, const float* __restrict__ br,
                const float* __restrict__ mr, const float* __restrict__ vr,
                short* __restrict__ whi, short* __restrict__ wmid,
                short* __restrict__ rhi, short* __restrict__ rmid,
                float* __restrict__ bias1, float* __restrict__ biasr) {
    int i = blockIdx.x * 256 + threadIdx.x;
    if (i < 294912) {                 // 256 oc * 128 ic * 9 taps
        int n = i / 1152, rem = i % 1152;
        int ic = rem / 9, tap = rem % 9;
        float sc = g1[n] / sqrtf(v1[n] + 1e-5f);
        float wv = (w1[i] * sc) * 4096.0f;
        _Float16 h = (_Float16)wv;            // RNE
        float r1 = wv - (float)h;
        _Float16 m = (_Float16)r1;
        int kb = ic >> 5, q = (ic >> 3) & 3, j = ic & 7;
        size_t f = ((((size_t)(kb * 9 + tap)) * 4 + q) * 256 + n) * 8 + j;
        whi[f]  = __builtin_bit_cast(short, h);
        wmid[f] = __builtin_bit_cast(short, m);
    }
    if (i < 32768) {                  // 256 oc * 128 ic
        int n = i >> 7, ic = i & 127;
        float sc = gr[n] / sqrtf(vr[n] + 1e-5f);
        float wv = (wres[i] * sc) * 4096.0f;
        _Float16 h = (_Float16)wv;
        float r1 = wv - (float)h;
        _Float16 m = (_Float16)r1;
        int kb = ic >> 5, q = (ic >> 3) & 3, j = ic & 7;
        size_t f = (((size_t)kb * 4 + q) * 256 + n) * 8 + j;
        rhi[f]  = __builtin_bit_cast(short, h);
        rmid[f] = __builtin_bit_cast(short, m);
    }
    if (i < 256) {
        float sc1 = g1[i] / sqrtf(v1[i] + 1e-5f);
        bias1[i] = (b1[i] - m1[i] * sc1) * 4096.0f;
        float scr_ = gr[i] / sqrtf(vr[i] + 1e-5f);
        biasr[i] = (br[i] - mr[i] * scr_) * 4096.0f;
    }
}

// ---------------------------------------------------------------------------
// k_proj (per t): x_in = x[t] + (first ? 0 : x_out);  3x3 conv 2->128 + BN +
// LIF(vp, skip-read at t=0).  Spikes BIT-PACKED: s1t[b][pix][16B record],
// byte icb holds ic icb*8+bit.  (r9-proven body + r10 bit store)
// grid (4,16,16), block 256.
// ---------------------------------------------------------------------------
__global__ __launch_bounds__(256)
void k_proj(const float* __restrict__ xt, const float* __restrict__ xout,
            const float* __restrict__ wp,
            const float* __restrict__ g, const float* __restrict__ bb,
            const float* __restrict__ mm, const float* __restrict__ vv,
            float* __restrict__ vp, unsigned char* __restrict__ s1t, int first) {
    __shared__ float xin[2 * 10 * 36];
    const int tid = threadIdx.x;
    const int b   = blockIdx.z >> 2;
    const int ocq = blockIdx.z & 3;
    const int gy0 = blockIdx.y * 8, gx0 = blockIdx.x * 32;

    for (int i = tid; i < 680; i += 256) {
        int ch = i / 340, rem = i % 340;
        int r = rem / 34, c = rem % 34;
        int gy = gy0 - 1 + r, gx = gx0 - 1 + c;
        float val = 0.f;
        if (gy >= 0 && gy < 128 && gx >= 0 && gx < 128) {
            int idx = ((b * 2 + ch) << 14) + (gy << 7) + gx;
            val = xt[idx];
            if (!first) val += xout[idx];
        }
        xin[(ch * 10 + r) * 36 + c] = val;
    }
    __syncthreads();

    const int prow = tid >> 5, pcol = tid & 31;
    float xw[2][3][3];
#pragma unroll
    for (int ch = 0; ch < 2; ++ch)
#pragma unroll
        for (int ky = 0; ky < 3; ++ky)
#pragma unroll
            for (int kx = 0; kx < 3; ++kx)
                xw[ch][ky][kx] = xin[(ch * 10 + prow + ky) * 36 + pcol + kx];

    const int pix = ((gy0 + prow) << 7) + gx0 + pcol;
    const int oc_beg = ocq * 32;
    unsigned int pk = 0u;
#pragma unroll
    for (int oo = 0; oo < 32; ++oo) {
        const int oc = oc_beg + oo;
        float acc = 0.f;
#pragma unroll
        for (int ch = 0; ch < 2; ++ch)
#pragma unroll
            for (int ky = 0; ky < 3; ++ky)
#pragma unroll
                for (int kx = 0; kx < 3; ++kx)
                    acc = fmaf(wp[((oc * 2 + ch) * 3 + ky) * 3 + kx], xw[ch][ky][kx], acc);
        float sc = g[oc] / sqrtf(vv[oc] + 1e-5f);
        float h  = (acc - mm[oc]) * sc + bb[oc];
        int idx = ((b * 128 + oc) << 14) + pix;
        float v = first ? 0.f : vp[idx];
        v = v + (h - v) * 0.5f;
        bool s = (v >= 1.0f);
        vp[idx] = s ? 0.f : v;
        pk |= (s ? 1u : 0u) << oo;
    }
    *(unsigned int*)(s1t + ((((size_t)b << 14) + pix) << 4) + ocq * 4) = pk;
}

// ---------------------------------------------------------------------------
// k_temp (per t): 3x3 conv 128->2 + BN + LIF(vtm, skip-read at t=0); writes
// x_out spikes (float).  Bit-packed s1 reads, split-K over ic.  (r9/r10 body)
// grid (128 rows, B), block 256.
// ---------------------------------------------------------------------------
__global__ __launch_bounds__(256)
void k_temp(const unsigned char* __restrict__ s1t, const float* __restrict__ wt,
            const float* __restrict__ g, const float* __restrict__ bb,
            const float* __restrict__ mm, const float* __restrict__ vv,
            float* __restrict__ vtm, float* __restrict__ xout, int first) {
    __shared__ unsigned char sl[49152];   // [icb 16][r 3][p 128] * 8B
    __shared__ float wls[2304];
    __shared__ float red[256];
    const int tid = threadIdx.x;
    const int b   = blockIdx.y;
    const int y0  = blockIdx.x;

    for (int i = tid; i < 2304; i += 256) wls[i] = wt[i];

    for (int i = tid; i < 384; i += 256) {     // 3 rows * 128 px, bit-packed
        int r = i >> 7, px = i & 127;
        int gy = y0 - 1 + r;
        uint4 d = make_uint4(0u, 0u, 0u, 0u);
        if (gy >= 0 && gy < 128)
            d = *(const uint4*)(s1t + ((((size_t)b << 14) + (gy << 7) + px) << 4));
        unsigned int bs[4] = {d.x, d.y, d.z, d.w};
#pragma unroll
        for (int icb = 0; icb < 16; ++icb) {
            unsigned int v8 = (bs[icb >> 2] >> ((icb & 3) * 8)) & 0xFFu;
            unsigned int lo = (v8 & 1u) | ((v8 & 2u) << 7) | ((v8 & 4u) << 14) | ((v8 & 8u) << 21);
            unsigned int hi = ((v8 >> 4) & 1u) | ((v8 & 32u) << 3) | ((v8 & 64u) << 10) | ((v8 & 128u) << 17);
            *(uint2*)&sl[(((icb * 3) + r) * 128 + (px ^ (icb & 7))) * 8] = make_uint2(lo, hi);
        }
    }
    __syncthreads();

    const int x = tid & 127, hf = tid >> 7;
    float a0 = 0.f, a1 = 0.f;
#pragma unroll 1
    for (int ii = 0; ii < 8; ++ii) {
        const int icb = hf * 8 + ii;
        int sw = icb & 7;
        const float* w0 = &wls[icb * 72];
        const float* w1_ = &wls[1152 + icb * 72];
#pragma unroll
        for (int dy = 0; dy < 3; ++dy) {
#pragma unroll
            for (int dx = 0; dx < 3; ++dx) {
                int xx = x - 1 + dx;
                if (xx < 0 || xx > 127) continue;
                uint2 d = *(const uint2*)&sl[((icb * 3 + dy) * 128 + (xx ^ sw)) * 8];
                int tap = dy * 3 + dx;
#pragma unroll
                for (int j = 0; j < 4; ++j) {
                    float f0 = (float)((d.x >> (8 * j)) & 0xFFu);
                    float f1 = (float)((d.y >> (8 * j)) & 0xFFu);
                    a0 = fmaf(w0[j * 9 + tap],        f0, a0);
                    a0 = fmaf(w0[(4 + j) * 9 + tap],  f1, a0);
                    a1 = fmaf(w1_[j * 9 + tap],       f0, a1);
                    a1 = fmaf(w1_[(4 + j) * 9 + tap], f1, a1);
                }
            }
        }
    }
    if (hf) { red[x] = a0; red[128 + x] = a1; }
    __syncthreads();
    if (!hf) {
        a0 += red[x]; a1 += red[128 + x];
#pragma unroll
        for (int oc = 0; oc < 2; ++oc) {
            float acc = (oc == 0) ? a0 : a1;
            float sc = g[oc] / sqrtf(vv[oc] + 1e-5f);
            float yv = (acc - mm[oc]) * sc + bb[oc];
            int idx = ((b * 2 + oc) << 14) + (y0 << 7) + x;
            float v = first ? 0.f : vtm[idx];
            v = v + (yv - v) * 0.5f;
            bool s = (v >= 1.0f);
            vtm[idx]  = s ? 0.f : v;
            xout[idx] = s ? 1.0f : 0.f;
        }
    }
}

// ---------------------------------------------------------------------------
// k_fused (ROUND 11): spike BITS for ALL 4 t live in LDS (4t x 204px x 16B
// = 13KB) staged ONCE -> ONE barrier in the whole kernel.  Per K-step each
// lane reads its spike byte from LDS (4 q-lanes share a dword -> broadcast,
// conflict-free) and expands 8 bits -> half8 in VALU, co-issued with MFMA
// (separate pipes).  No per-t restaging, no per-t barriers; waves free-run
// across the t loop.  fp16 2-plane weights = A, spikes = B, direct stores.
// grid (4 oc-tiles, 512 px-tiles), block 256 = 4 waves.
// ---------------------------------------------------------------------------
__global__ __launch_bounds__(256, 3)
void k_fused(const unsigned char* __restrict__ s1c,
             const short* __restrict__ whi, const short* __restrict__ wmid,
             const short* __restrict__ rhi, const short* __restrict__ rmid,
             const float* __restrict__ bias1, const float* __restrict__ biasr,
             float* __restrict__ out) {
    __shared__ __align__(16) unsigned char bl[13056];   // [t 4][p 204][16B]

    const int tid = threadIdx.x;
    const int oc0 = blockIdx.x * 64;
    const int yb = blockIdx.y;
    const int b = yb >> 7, ry = (yb >> 2) & 31, cx = yb & 3;
    const int gy0 = ry * 4, gx0 = cx * 32;

    const int w   = tid >> 6, l = tid & 63;
    const int q   = l >> 4,  ln = l & 15;
    const int woc = w >> 1,  wpx = w & 1;

    f32x4 ba[2], brr[2];
#pragma unroll
    for (int mt = 0; mt < 2; ++mt)
#pragma unroll
        for (int rg = 0; rg < 4; ++rg) {
            int oc = oc0 + woc * 32 + mt * 16 + q * 4 + rg;
            ba[mt][rg]  = bias1[oc];
            brr[mt][rg] = biasr[oc];
        }

    const size_t wofs = ((size_t)q * 256 + oc0 + woc * 32 + ln) * 8;

    int pb[4], po[4];
#pragma unroll
    for (int nt = 0; nt < 4; ++nt) {
        int px = wpx * 64 + nt * 16 + ln;
        int prow = px >> 5, pcol = px & 31;
        pb[nt] = prow * 34 + pcol;                 // halo-tile entry index
        po[nt] = ((gy0 + prow) << 7) + gx0 + pcol; // out pixel offset
    }

    // ---- stage ALL FOUR t's bit tiles (halo 6x34) -> 13KB LDS, once ----
    for (int cc = tid; cc < 816; cc += 256) {      // 816 = 4t * 204p
        int t = cc / 204, p = cc - t * 204;
        int r = p / 34, c = p - r * 34;
        int gy = gy0 - 1 + r, gx = gx0 - 1 + c;
        uint4 d = make_uint4(0u, 0u, 0u, 0u);
        if (gy >= 0 && gy < 128 && gx >= 0 && gx < 128)
            d = *(const uint4*)(s1c + (size_t)t * 1048576 +
                                ((((size_t)b << 14) + (gy << 7) + gx) << 4));
        *(uint4*)(bl + cc * 16) = d;
    }
    __syncthreads();   // the ONLY barrier

    float va[4][2][4], vres[4][2][4];
#pragma unroll
    for (int nt = 0; nt < 4; ++nt)
#pragma unroll
        for (int mt = 0; mt < 2; ++mt)
#pragma unroll
            for (int rg = 0; rg < 4; ++rg) { va[nt][mt][rg] = 0.f; vres[nt][mt][rg] = 0.f; }

#pragma unroll 1
    for (int t = 0; t < 4; ++t) {
        const unsigned char* blt = bl + t * 3264;   // 204*16

        f32x4 acc[4][2], accr[4][2];
#pragma unroll
        for (int nt = 0; nt < 4; ++nt)
#pragma unroll
            for (int mt = 0; mt < 2; ++mt) { acc[nt][mt] = ba[mt]; accr[nt][mt] = brr[mt]; }

        const short* bh = whi  + wofs;
        const short* bm = wmid + wofs;

#pragma unroll 1
        for (int kb = 0; kb < 4; ++kb) {
            const int byi = kb * 4 + q;             // spike byte in px record
#pragma unroll
            for (int ky = 0; ky < 3; ++ky) {
#pragma unroll
                for (int kx = 0; kx < 3; ++kx) {
                    half8 B4[4];
#pragma unroll
                    for (int nt = 0; nt < 4; ++nt) {
                        unsigned int v8 = blt[(pb[nt] + ky * 34 + kx) * 16 + byi];
                        uint4 pk;                   // fp16 1.0 = 0x3C00
                        pk.x = ((v8 & 1u)          | ((v8 & 2u)   << 15)) * 0x3C00u;
                        pk.y = (((v8 >> 2) & 1u)   | ((v8 & 8u)   << 13)) * 0x3C00u;
                        pk.z = (((v8 >> 4) & 1u)   | ((v8 & 32u)  << 11)) * 0x3C00u;
                        pk.w = (((v8 >> 6) & 1u)   | ((v8 & 128u) << 9 )) * 0x3C00u;
                        B4[nt] = __builtin_bit_cast(half8, pk);
                    }
                    half8 AH[2], AM[2];
#pragma unroll
                    for (int mt = 0; mt < 2; ++mt) {
                        AH[mt] = *(const half8*)(bh + mt * 128);
                        AM[mt] = *(const half8*)(bm + mt * 128);
                    }
#pragma unroll
                    for (int nt = 0; nt < 4; ++nt)
#pragma unroll
                        for (int mt = 0; mt < 2; ++mt) {
                            acc[nt][mt] = __builtin_amdgcn_mfma_f32_16x16x32_f16(AH[mt], B4[nt], acc[nt][mt], 0, 0, 0);
                            acc[nt][mt] = __builtin_amdgcn_mfma_f32_16x16x32_f16(AM[mt], B4[nt], acc[nt][mt], 0, 0, 0);
                        }
                    if (ky == 1 && kx == 1) {   // 1x1 res conv on the center tap
                        half8 RH[2], RM[2];
#pragma unroll
                        for (int mt = 0; mt < 2; ++mt) {
                            RH[mt] = *(const half8*)(rhi  + wofs + (size_t)kb * 8192 + mt * 128);
                            RM[mt] = *(const half8*)(rmid + wofs + (size_t)kb * 8192 + mt * 128);
                        }
#pragma unroll
                        for (int nt = 0; nt < 4; ++nt)
#pragma unroll
                            for (int mt = 0; mt < 2; ++mt) {
                                accr[nt][mt] = __builtin_amdgcn_mfma_f32_16x16x32_f16(RH[mt], B4[nt], accr[nt][mt], 0, 0, 0);
                                accr[nt][mt] = __builtin_amdgcn_mfma_f32_16x16x32_f16(RM[mt], B4[nt], accr[nt][mt], 0, 0, 0);
                            }
                    }
                    bh += 8192; bm += 8192;
                }
            }
        }

        // ---- LIF (both paths; undo 2^12 plane scale) + direct stores ----
        const float ds_ = 0.000244140625f;   // 2^-12, exact
        const size_t tb = ((size_t)((t * 4 + b) * 256 + oc0)) << 14;
#pragma unroll
        for (int mt = 0; mt < 2; ++mt)
#pragma unroll
            for (int rg = 0; rg < 4; ++rg) {
                const size_t ob = tb + ((size_t)(woc * 32 + mt * 16 + q * 4 + rg) << 14);
#pragma unroll
                for (int nt = 0; nt < 4; ++nt) {
                    float ha = acc[nt][mt][rg] * ds_;
                    float v = va[nt][mt][rg];
                    v = v + (ha - v) * 0.5f;
                    bool s = (v >= 1.0f);
                    va[nt][mt][rg] = s ? 0.f : v;
                    float sa = s ? 1.f : 0.f;

                    float hr = accr[nt][mt][rg] * ds_;
                    float u = vres[nt][mt][rg];
                    u = u + (hr - u) * 0.5f;
                    bool sr_ = (u >= 1.0f);
                    vres[nt][mt][rg] = sr_ ? 0.f : u;

                    out[ob + po[nt]] = sa + (sr_ ? 1.f : 0.f);
                }
            }
    }
}

// ---------------------------------------------------------------------------
// Workspace layout (bytes), total 40,110,080 (well under the proven 69.5MB):
//   s1c(bits) @ 0           4,194,304   [T][B][pix][16B]
//   vp        @ 4,194,304  33,554,432   (t=0 skip-read -> no memset)
//   vtm       @ 37,748,736    524,288   (t=0 skip-read)
//   xout      @ 38,273,024    524,288   (t=0 not read)
//   whi       @ 38,797,312    589,824
//   wmid      @ 39,387,136    589,824
//   rhi       @ 39,976,960     65,536
//   rmid      @ 40,042,496     65,536
//   bias1     @ 40,108,032      1,024
//   biasr     @ 40,109,056      1,024
// ---------------------------------------------------------------------------
extern "C" void kernel_launch(void* const* d_in, const int* in_sizes, int n_in,
                              void* d_out, int out_size, void* d_ws, size_t ws_size,
                              hipStream_t stream) {
    const float* x      = (const float*)d_in[0];
    const float* w_proj = (const float*)d_in[1];
    const float* g0 = (const float*)d_in[2];
    const float* b0 = (const float*)d_in[3];
    const float* m0 = (const float*)d_in[4];
    const float* v0 = (const float*)d_in[5];
    const float* w_temp = (const float*)d_in[6];
    const float* gt = (const float*)d_in[7];
    const float* bt = (const float*)d_in[8];
    const float* mt = (const float*)d_in[9];
    const float* vt = (const float*)d_in[10];
    const float* w1 = (const float*)d_in[11];
    const float* g1 = (const float*)d_in[12];
    const float* b1 = (const float*)d_in[13];
    const float* m1 = (const float*)d_in[14];
    const float* v1 = (const float*)d_in[15];
    const float* w_res = (const float*)d_in[16];
    const float* gr = (const float*)d_in[17];
    const float* br = (const float*)d_in[18];
    const float* mr = (const float*)d_in[19];
    const float* vr = (const float*)d_in[20];

    char* ws = (char*)d_ws;
    unsigned char* s1c = (unsigned char*)ws;
    float* vp    = (float*)(ws + 4194304);
    float* vtm   = (float*)(ws + 37748736);
    float* xout  = (float*)(ws + 38273024);
    short* whi   = (short*)(ws + 38797312);
    short* wmid  = (short*)(ws + 39387136);
    short* rhi   = (short*)(ws + 39976960);
    short* rmid  = (short*)(ws + 40042496);
    float* bias1 = (float*)(ws + 40108032);
    float* biasr = (float*)(ws + 40109056);

    // weight reorder first: independent of stage A, off the critical tail
    k_reorder2<<<dim3(1152), dim3(256), 0, stream>>>(
        w1, w_res, g1, b1, m1, v1, gr, br, mr, vr,
        whi, wmid, rhi, rmid, bias1, biasr);

    for (int t = 0; t < 4; ++t) {
        const float* xt = x + (size_t)t * 131072;
        unsigned char* s1t = s1c + (size_t)t * 1048576;
        k_proj<<<dim3(4, 16, 16), dim3(256), 0, stream>>>(
            xt, xout, w_proj, g0, b0, m0, v0, vp, s1t, t == 0);
        k_temp<<<dim3(128, 4), dim3(256), 0, stream>>>(
            s1t, w_temp, gt, bt, mt, vt, vtm, xout, t == 0);
    }

    k_fused<<<dim3(4, 512), dim3(256), 0, stream>>>(
        s1c, whi, wmid, rhi, rmid, bias1, biasr, (float*)d_out);
}